// Round 1
// 419.235 us; speedup vs baseline: 1.1421x; 1.1421x over previous
//
#include <hip/hip_runtime.h>
#include <hip/hip_bf16.h>
#include <stdint.h>

typedef unsigned short u16;
typedef unsigned int u32;
typedef __bf16 bf16x8 __attribute__((ext_vector_type(8)));
typedef float f32x4 __attribute__((ext_vector_type(4)));

#define M_ROWS 32768   // bs*seq
#define DIM    1024    // inp_dim
#define NPROJ  64
#define NBINS  20
#define FDIM   1280    // NPROJ*NBINS
#define EDIM   1024    // emb_dim

// round-to-nearest-even f32 -> bf16 (no NaNs in this problem)
__device__ __forceinline__ u16 f2bf(float f) {
    union { float f; u32 u; } v; v.f = f;
    return (u16)((v.u + 0x7FFFu + ((v.u >> 16) & 1u)) >> 16);
}

__device__ __forceinline__ float wave_sum(float v) {
    #pragma unroll
    for (int o = 32; o > 0; o >>= 1) v += __shfl_down(v, o, 64);
    return v;
}

// ---------------------------------------------------------------------------
// K1: normalize proj_weight rows, store TRANSPOSED k-major: wnt[k][j], fp32.
// 64 blocks x 256 threads (one block per proj row).
__global__ void k_norm_w(const float* __restrict__ w, float* __restrict__ wnt) {
    int j = blockIdx.x;
    int t = threadIdx.x;
    float4 v = ((const float4*)(w + (size_t)j * DIM))[t];
    float ss = v.x*v.x + v.y*v.y + v.z*v.z + v.w*v.w;
    ss = wave_sum(ss);
    __shared__ float red[4];
    if ((t & 63) == 0) red[t >> 6] = ss;
    __syncthreads();
    float rn = 1.0f / fmaxf(sqrtf(red[0] + red[1] + red[2] + red[3]), 1e-12f);
    int k = t * 4;
    wnt[(size_t)(k+0)*NPROJ + j] = v.x * rn;
    wnt[(size_t)(k+1)*NPROJ + j] = v.y * rn;
    wnt[(size_t)(k+2)*NPROJ + j] = v.z * rn;
    wnt[(size_t)(k+3)*NPROJ + j] = v.w * rn;
}

// ---------------------------------------------------------------------------
// K3: emb_weight fp32 -> bf16, same [EDIM][FDIM] layout. 1280 blocks.
__global__ void k_cvt(const float* __restrict__ s, u16* __restrict__ d) {
    int i = blockIdx.x * 256 + threadIdx.x;
    float4 v = ((const float4*)s)[i];
    ushort4 o; o.x = f2bf(v.x); o.y = f2bf(v.y); o.z = f2bf(v.z); o.w = f2bf(v.w);
    ((ushort4*)d)[i] = o;
}

// ---------------------------------------------------------------------------
// K_FUSED: rnx + GEMM1 + RBF/top4/normalize, x read ONCE, p stays in LDS.
// Block: 64 rows x all 64 projs, BK=32, 256 threads, thread tile 4x4.
// rnx fused: staging map has thread t always loading row r = t>>2 -> per-thread
//   partial sum-of-squares, 4-lane shfl reduce at the end (exact, each elem once).
// act fused: NPROJ == block col-tile, so p[64][64] is complete per block.
//   Act phase: thread t owns proj pj = t&63 (constant!), rows it*4+(t>>6).
__global__ __launch_bounds__(256) void k_fused(
        const float* __restrict__ x, const float* __restrict__ wnt,
        const float* __restrict__ mean, u16* __restrict__ z) {
    __shared__ float xs[32][64];   // [k][row]
    __shared__ float wst[32][64];  // [k][j]
    __shared__ float pl[64][65];   // p tile, +1 pad
    __shared__ float rnl[64];
    int t = threadIdx.x;
    int bm = blockIdx.x * 64;
    int tr = t >> 4;       // rows tr*4..+3
    int tc = t & 15;       // projs tc*4..+3
    float acc[4][4] = {};
    float ssl = 0.f;

    for (int k0 = 0; k0 < DIM; k0 += 32) {
        #pragma unroll
        for (int u = 0; u < 2; u++) {
            int f = t * 2 + u;                 // 0..511
            int r  = f >> 3;                   // == t>>2 for both u
            int kc = (f & 7) * 4;
            float4 v = *(const float4*)(x + (size_t)(bm + r) * DIM + k0 + kc);
            ssl += v.x*v.x + v.y*v.y + v.z*v.z + v.w*v.w;
            xs[kc+0][r] = v.x; xs[kc+1][r] = v.y; xs[kc+2][r] = v.z; xs[kc+3][r] = v.w;
            int wk = f >> 4, wj = (f & 15) * 4;
            *(float4*)&wst[wk][wj] = *(const float4*)(wnt + (size_t)(k0 + wk) * NPROJ + wj);
        }
        __syncthreads();
        #pragma unroll 8
        for (int k = 0; k < 32; k++) {
            float4 a = *(const float4*)&xs[k][tr * 4];
            float4 b = *(const float4*)&wst[k][tc * 4];
            float av[4] = {a.x, a.y, a.z, a.w};
            float bv[4] = {b.x, b.y, b.z, b.w};
            #pragma unroll
            for (int i = 0; i < 4; i++)
                #pragma unroll
                for (int j = 0; j < 4; j++)
                    acc[i][j] += av[i] * bv[j];
        }
        __syncthreads();
    }

    // --- row 1/max(||x||,eps): threads 4r..4r+3 hold partials for row r
    ssl += __shfl_xor(ssl, 1, 64);
    ssl += __shfl_xor(ssl, 2, 64);
    if ((t & 3) == 0) rnl[t >> 2] = 1.0f / fmaxf(sqrtf(ssl), 1e-12f);
    __syncthreads();

    // --- scale + stash p in LDS
    #pragma unroll
    for (int i = 0; i < 4; i++) {
        float rn = rnl[tr * 4 + i];
        #pragma unroll
        for (int j = 0; j < 4; j++)
            pl[tr * 4 + i][tc * 4 + j] = acc[i][j] * rn;
    }

    // per-thread proj is constant across the act loop -> means live in regs
    int pj = t & 63;
    float mv[NBINS];
    #pragma unroll
    for (int i = 0; i < 5; i++) {
        float4 m4 = *(const float4*)(mean + pj * NBINS + i * 4);  // 80B-aligned
        mv[i*4+0] = m4.x; mv[i*4+1] = m4.y; mv[i*4+2] = m4.z; mv[i*4+3] = m4.w;
    }
    __syncthreads();

    // --- RBF + top-4(keep ties) + L2 norm + bf16 pack, 16 groups/thread
    #pragma unroll 2
    for (int it = 0; it < 16; it++) {
        int row = it * 4 + (t >> 6);           // wave-uniform row
        float pv = pl[row][pj];                // conflict-free (pad 65)
        float act[NBINS];
        float top0 = -1e30f, top1 = -1e30f, top2 = -1e30f, top3 = -1e30f;
        #pragma unroll
        for (int b = 0; b < NBINS; b++) {
            float d = pv - mv[b];
            float a = __expf(-50.0f * d * d);   // 0.5/sigma2 = 50
            act[b] = a;
            if (a > top3) {
                if (a > top0)      { top3 = top2; top2 = top1; top1 = top0; top0 = a; }
                else if (a > top1) { top3 = top2; top2 = top1; top1 = a; }
                else if (a > top2) { top3 = top2; top2 = a; }
                else               { top3 = a; }
            }
        }
        float ss = 0.f;
        #pragma unroll
        for (int b = 0; b < NBINS; b++) {
            float a = (act[b] >= top3) ? act[b] : 0.0f;   // keep ties
            act[b] = a;
            ss += a * a;
        }
        float rn = 1.0f / fmaxf(sqrtf(ss), 1e-12f);
        u32* zp = (u32*)(z + ((size_t)(bm + row) * FDIM + pj * NBINS)); // 40B chunks, dword aligned
        #pragma unroll
        for (int i = 0; i < 10; i++) {
            u32 lo = f2bf(act[2*i]   * rn);
            u32 hi = f2bf(act[2*i+1] * rn);
            zp[i] = lo | (hi << 16);
        }
    }
}

// ---------------------------------------------------------------------------
// K6: GEMM2 bf16 MFMA (m97 structure): C[m][n] = sum_k A[m][k]*B[n][k]
// A = z [32768 x 1280], B = embW bf16 [1024 x 1280], C fp32 [32768 x 1024].
// 128x128 tile, BK=32, 4 waves in 2x2, each wave 4x4 of 16x16x32 MFMA.
// XCD swizzle (T1): hw dispatch id round-robins XCDs; remap so each XCD gets
// a contiguous chunk of M-tiles -> the 8 blocks sharing an A-panel land on
// ONE XCD's L2 instead of 8. nwg=2048, %8==0 -> bijective.
__device__ __forceinline__ void gl_lds16(const void* g, void* l) {
    __builtin_amdgcn_global_load_lds(
        (const __attribute__((address_space(1))) void*)g,
        (__attribute__((address_space(3))) void*)l, 16, 0, 0);
}

__global__ __launch_bounds__(256) void k_gemm2(const u16* __restrict__ A,
                                               const u16* __restrict__ B,
                                               float* __restrict__ C) {
    const int K = FDIM, N = EDIM;
    __shared__ u16 As[128 * 32];
    __shared__ u16 Bs[128 * 32];
    int t = threadIdx.x;
    int lane = t & 63, wave = t >> 6;
    int sfl  = (blockIdx.y << 3) | blockIdx.x;        // hw dispatch order (x fastest)
    int tile = ((sfl & 7) << 8) | (sfl >> 3);         // xcd*256 + idx-in-xcd
    int bm = (tile >> 3) * 128;                       // 0..255 M-tiles
    int bn = (tile & 7) * 128;                        // 0..7   N-tiles
    int wm = (wave >> 1) * 64, wn = (wave & 1) * 64;
    int m16 = lane & 15, q = lane >> 4;

    f32x4 zero = {0.f, 0.f, 0.f, 0.f};
    f32x4 acc[4][4];
    #pragma unroll
    for (int i = 0; i < 4; i++)
        #pragma unroll
        for (int j = 0; j < 4; j++) acc[i][j] = zero;

    // staging map: thread t -> row sr (0..63, and +64), 8-elem chunk sc.
    // LDS byte offset = 1024*wave + 16*lane  (wave-uniform base + lane*16) ✓
    int sr = t >> 2;
    int sc = (t & 3) * 8;
    const u16* ga = A + (size_t)(bm + sr) * K + sc;
    const u16* gb = B + (size_t)(bn + sr) * K + sc;
    u16* la = &As[sr * 32 + sc];
    u16* lb = &Bs[sr * 32 + sc];

    for (int k0 = 0; k0 < K; k0 += 32) {
        gl_lds16(ga + k0,                 la);
        gl_lds16(ga + k0 + (size_t)64*K,  la + 64 * 32);
        gl_lds16(gb + k0,                 lb);
        gl_lds16(gb + k0 + (size_t)64*K,  lb + 64 * 32);
        __syncthreads();   // compiler emits vmcnt(0) drain before s_barrier
        bf16x8 af[4], bfr[4];
        #pragma unroll
        for (int i = 0; i < 4; i++)
            af[i] = *(const bf16x8*)&As[(wm + i * 16 + m16) * 32 + q * 8];
        #pragma unroll
        for (int j = 0; j < 4; j++)
            bfr[j] = *(const bf16x8*)&Bs[(wn + j * 16 + m16) * 32 + q * 8];
        #pragma unroll
        for (int i = 0; i < 4; i++)
            #pragma unroll
            for (int j = 0; j < 4; j++)
                acc[i][j] = __builtin_amdgcn_mfma_f32_16x16x32_bf16(
                    af[i], bfr[j], acc[i][j], 0, 0, 0);
        __syncthreads();
    }
    // C/D layout: col = lane&15, row = q*4 + reg  [m89-verified]
    #pragma unroll
    for (int i = 0; i < 4; i++)
        #pragma unroll
        for (int j = 0; j < 4; j++)
            #pragma unroll
            for (int r = 0; r < 4; r++) {
                int row = bm + wm + i * 16 + q * 4 + r;
                int col = bn + wn + j * 16 + m16;
                C[(size_t)row * N + col] = acc[i][j][r];
            }
}

// ---------------------------------------------------------------------------
extern "C" void kernel_launch(void* const* d_in, const int* in_sizes, int n_in,
                              void* d_out, int out_size, void* d_ws, size_t ws_size,
                              hipStream_t stream) {
    const float* x    = (const float*)d_in[0];   // [32768][1024]
    const float* pw   = (const float*)d_in[1];   // [64][1024]
    const float* mean = (const float*)d_in[2];   // [64][20]
    const float* emb  = (const float*)d_in[3];   // [1024][1280]
    float* out = (float*)d_out;                  // [32768][1024] fp32

    char* ws = (char*)d_ws;
    u16*   z    = (u16*)(ws);                    // 83,886,080 B
    float* wnt  = (float*)(ws + 83886080);       //    262,144 B (k-major)
    u16*   embW = (u16*)(ws + 84148224);         //  2,621,440 B
    // total: 86,769,664 B

    k_norm_w<<<64, 256, 0, stream>>>(pw, wnt);
    k_cvt<<<(EDIM * FDIM / 4) / 256, 256, 0, stream>>>(emb, embW);
    k_fused<<<M_ROWS / 64, 256, 0, stream>>>(x, wnt, mean, z);
    k_gemm2<<<dim3(EDIM / 128, M_ROWS / 128), 256, 0, stream>>>(z, embW, out);
}

// Round 2
// 403.978 us; speedup vs baseline: 1.1852x; 1.0378x over previous
//
#include <hip/hip_runtime.h>
#include <hip/hip_bf16.h>
#include <stdint.h>

typedef unsigned short u16;
typedef unsigned int u32;
typedef unsigned long long u64;
typedef __bf16 bf16x8 __attribute__((ext_vector_type(8)));
typedef _Float16 f16x8 __attribute__((ext_vector_type(8)));
typedef float f32x4 __attribute__((ext_vector_type(4)));

#define M_ROWS 32768   // bs*seq
#define DIM    1024    // inp_dim
#define NPROJ  64
#define NBINS  20
#define FDIM   1280    // NPROJ*NBINS
#define EDIM   1024    // emb_dim

// round-to-nearest-even f32 -> bf16 (no NaNs in this problem)
__device__ __forceinline__ u16 f2bf(float f) {
    union { float f; u32 u; } v; v.f = f;
    return (u16)((v.u + 0x7FFFu + ((v.u >> 16) & 1u)) >> 16);
}

__device__ __forceinline__ float wave_sum(float v) {
    #pragma unroll
    for (int o = 32; o > 0; o >>= 1) v += __shfl_down(v, o, 64);
    return v;
}

__device__ __forceinline__ void gl_lds16(const void* g, void* l) {
    __builtin_amdgcn_global_load_lds(
        (const __attribute__((address_space(1))) void*)g,
        (__attribute__((address_space(3))) void*)l, 16, 0, 0);
}

__device__ __forceinline__ f32x4 mfma16(f16x8 a, f16x8 b, f32x4 c) {
    return __builtin_amdgcn_mfma_f32_16x16x32_f16(a, b, c, 0, 0, 0);
}

// scaled f16 split: f = hi + lo*2^-12, lo kept in normal f16 range.
__device__ __forceinline__ void split8(const float* f, f16x8& hi, f16x8& lo) {
    #pragma unroll
    for (int e = 0; e < 8; e++) {
        _Float16 h = (_Float16)f[e];
        hi[e] = h;
        lo[e] = (_Float16)((f[e] - (float)h) * 4096.0f);
    }
}

// ---------------------------------------------------------------------------
// K1: normalize proj_weight rows, split to f16 hi / scaled-lo, and store as
// PRE-SWIZZLED per-K-step tile images so k_fused can global_load_lds them
// linearly and read fragments with the XOR swizzle (G21: both-sides).
// Image: 16 steps x [64 proj][64 k] f16, byte-in-tile = p*128 + (k2 ^ ((p&7)<<4)).
// 64 blocks x 256 threads (one block per proj row, thread t -> k=4t..4t+3).
__global__ void k_norm_w(const float* __restrict__ w, u16* __restrict__ wswh,
                         u16* __restrict__ wswl) {
    int j = blockIdx.x;
    int t = threadIdx.x;
    float4 v = ((const float4*)(w + (size_t)j * DIM))[t];
    float ss = v.x*v.x + v.y*v.y + v.z*v.z + v.w*v.w;
    ss = wave_sum(ss);
    __shared__ float red[4];
    if ((t & 63) == 0) red[t >> 6] = ss;
    __syncthreads();
    float rn = 1.0f / fmaxf(sqrtf(red[0] + red[1] + red[2] + red[3]), 1e-12f);
    float wn[4] = {v.x*rn, v.y*rn, v.z*rn, v.w*rn};
    u64 hp = 0, lp = 0;
    #pragma unroll
    for (int e = 0; e < 4; e++) {
        _Float16 h = (_Float16)wn[e];
        _Float16 l = (_Float16)((wn[e] - (float)h) * 4096.0f);
        union { _Float16 f; u16 u; } ch, cl;
        ch.f = h; cl.f = l;
        hp |= (u64)ch.u << (16 * e);
        lp |= (u64)cl.u << (16 * e);
    }
    int s   = t >> 4;            // K-step (64 fp32 k per step)
    int kk2 = (t & 15) * 8;      // byte col within tile row (k*2)
    int off = s * 8192 + j * 128 + (kk2 ^ ((j & 7) << 4));  // 8B write stays in 16B swz unit
    *(u64*)((char*)wswh + off) = hp;
    *(u64*)((char*)wswl + off) = lp;
}

// ---------------------------------------------------------------------------
// K3: emb_weight fp32 -> bf16, same [EDIM][FDIM] layout. 1280 blocks.
__global__ void k_cvt(const float* __restrict__ s, u16* __restrict__ d) {
    int i = blockIdx.x * 256 + threadIdx.x;
    float4 v = ((const float4*)s)[i];
    ushort4 o; o.x = f2bf(v.x); o.y = f2bf(v.y); o.z = f2bf(v.z); o.w = f2bf(v.w);
    ((ushort4*)d)[i] = o;
}

// ---------------------------------------------------------------------------
// K_FUSED v2: rnx + GEMM1(MFMA, exact f16-split) + RBF/top4/normalize.
// Block = 64 rows x 64 projs, 4 waves x 16 rows. 512 blocks (2/CU).
// A fragments come straight from registers: lane (m16,q) owns row wm+m16,
// k-chunk q*8+ks*32 -> x read ONCE, coalesced, no A LDS. Row sum-of-squares
// accumulates on the same registers; q-group shuffle reduce gives rnx.
// p = accA + accB/4096, scaled by rnx, redistributed via padded LDS tile;
// act phase: thread owns (row, 4 consecutive proj groups) -> 160B z writes.
__global__ __launch_bounds__(256) void k_fused(const float* __restrict__ x,
        const u16* __restrict__ wswh, const u16* __restrict__ wswl,
        const float* __restrict__ mean, u16* __restrict__ z) {
    __shared__ u16 Bh[2][4096];      // 8KB/buf: [64 proj][64 k] f16, row-swizzled
    __shared__ u16 Bl[2][4096];
    __shared__ float pl[64 * 68];    // stride 68: 2-way (free) banks both phases
    __shared__ float mlds[64 * 21];  // mean, stride 21 (2-way banks in act)
    __shared__ float rnl[64];

    int t = threadIdx.x;
    int lane = t & 63, wave = t >> 6;
    int m16 = lane & 15, q = lane >> 4;
    int bm = blockIdx.x * 64;
    int wm = wave * 16;
    const float* xr = x + (size_t)(bm + wm + m16) * DIM;   // this lane's A row

    // stage means (read in act phase only; any later barrier covers)
    for (int i = t; i < 64 * 21; i += 256) {
        int j = i / 21, b = i - j * 21;
        if (b < 20) mlds[i] = mean[j * 20 + b];
    }

    f32x4 accA[4], accB[4];
    #pragma unroll
    for (int j = 0; j < 4; j++) { accA[j] = (f32x4){0,0,0,0}; accB[j] = (f32x4){0,0,0,0}; }
    float ssl = 0.f;

    // prologue: stage B(0), load A(0)
    gl_lds16(wswh + (size_t)t * 8,        &Bh[0][t * 8]);
    gl_lds16(wswh + 2048 + (size_t)t * 8, &Bh[0][2048 + t * 8]);
    gl_lds16(wswl + (size_t)t * 8,        &Bl[0][t * 8]);
    gl_lds16(wswl + 2048 + (size_t)t * 8, &Bl[0][2048 + t * 8]);
    float4 c0 = *(const float4*)(xr + q * 8);
    float4 c1 = *(const float4*)(xr + q * 8 + 4);
    float4 c2 = *(const float4*)(xr + q * 8 + 32);
    float4 c3 = *(const float4*)(xr + q * 8 + 36);

    for (int s = 0; s < 16; s++) {
        __syncthreads();   // B(s) staged, A(s) regs arrived (vmcnt drain)

        float4 n0, n1, n2, n3;
        if (s < 15) {
            // issue next tile's loads BEFORE the MFMAs: they stay in flight
            // across this iteration's compute and next iteration's barrier.
            const u16* sh = wswh + (size_t)(s + 1) * 4096;
            const u16* sl = wswl + (size_t)(s + 1) * 4096;
            u16* dh = &Bh[(s + 1) & 1][0];
            u16* dl = &Bl[(s + 1) & 1][0];
            gl_lds16(sh + t * 8,        dh + t * 8);
            gl_lds16(sh + 2048 + t * 8, dh + 2048 + t * 8);
            gl_lds16(sl + t * 8,        dl + t * 8);
            gl_lds16(sl + 2048 + t * 8, dl + 2048 + t * 8);
            const float* xn = xr + (s + 1) * 64 + q * 8;
            n0 = *(const float4*)(xn);
            n1 = *(const float4*)(xn + 4);
            n2 = *(const float4*)(xn + 32);
            n3 = *(const float4*)(xn + 36);
        }

        // row-norm partials from this step's 16 floats
        ssl += c0.x*c0.x + c0.y*c0.y + c0.z*c0.z + c0.w*c0.w;
        ssl += c1.x*c1.x + c1.y*c1.y + c1.z*c1.z + c1.w*c1.w;
        ssl += c2.x*c2.x + c2.y*c2.y + c2.z*c2.z + c2.w*c2.w;
        ssl += c3.x*c3.x + c3.y*c3.y + c3.z*c3.z + c3.w*c3.w;

        // A frags (ks=0: k q*8..+7, ks=1: +32)
        float av0[8] = {c0.x, c0.y, c0.z, c0.w, c1.x, c1.y, c1.z, c1.w};
        float av1[8] = {c2.x, c2.y, c2.z, c2.w, c3.x, c3.y, c3.z, c3.w};
        f16x8 ah[2], al[2];
        split8(av0, ah[0], al[0]);
        split8(av1, ah[1], al[1]);

        const char* bhp = (const char*)&Bh[s & 1][0];
        const char* blp = (const char*)&Bl[s & 1][0];
        #pragma unroll
        for (int ks = 0; ks < 2; ks++) {
            #pragma unroll
            for (int j = 0; j < 4; j++) {
                int P = j * 16 + m16;
                int off = P * 128 + ((q * 16 + ks * 64) ^ ((m16 & 7) << 4));
                f16x8 bh = *(const f16x8*)(bhp + off);
                f16x8 bl = *(const f16x8*)(blp + off);
                accA[j] = mfma16(ah[ks], bh, accA[j]);
                accB[j] = mfma16(ah[ks], bl, accB[j]);
                accB[j] = mfma16(al[ks], bh, accB[j]);
            }
        }
        c0 = n0; c1 = n1; c2 = n2; c3 = n3;
    }

    // --- rnx: 4 q-lanes of a row hold disjoint partials
    ssl += __shfl_xor(ssl, 16, 64);
    ssl += __shfl_xor(ssl, 32, 64);
    if (q == 0) rnl[wm + m16] = 1.0f / fmaxf(sqrtf(ssl), 1e-12f);
    __syncthreads();

    // --- p = (accA + accB*2^-12) * rnx -> pl   (C layout: row q*4+r, col m16)
    #pragma unroll
    for (int r = 0; r < 4; r++) {
        int row = wm + q * 4 + r;
        float rr = rnl[row];
        #pragma unroll
        for (int j = 0; j < 4; j++)
            pl[row * 68 + j * 16 + m16] =
                (accA[j][r] + accB[j][r] * 2.44140625e-4f) * rr;
    }
    __syncthreads();

    // --- act: thread owns projs 4c..4c+3 of rows rt+16*it -> 160B z chunks
    int c = t & 15;
    int rt = t >> 4;
    #pragma unroll 1
    for (int it = 0; it < 4; it++) {
        int row = rt + 16 * it;
        const float* prow = &pl[row * 68 + c * 4];
        float pp[4] = {prow[0], prow[1], prow[2], prow[3]};
        u32 packed[40];
        #pragma unroll
        for (int jj = 0; jj < 4; jj++) {
            float pv = pp[jj];
            const float* mj = &mlds[(c * 4 + jj) * 21];
            float act[NBINS];
            float top0 = -1e30f, top1 = -1e30f, top2 = -1e30f, top3 = -1e30f;
            #pragma unroll
            for (int b = 0; b < NBINS; b++) {
                float d = pv - mj[b];
                float a = __expf(-50.0f * d * d);   // 0.5/sigma2 = 50
                act[b] = a;
                if (a > top3) {
                    if (a > top0)      { top3 = top2; top2 = top1; top1 = top0; top0 = a; }
                    else if (a > top1) { top3 = top2; top2 = top1; top1 = a; }
                    else if (a > top2) { top3 = top2; top2 = a; }
                    else               { top3 = a; }
                }
            }
            float ss = 0.f;
            #pragma unroll
            for (int b = 0; b < NBINS; b++) {
                float a = (act[b] >= top3) ? act[b] : 0.0f;   // keep ties
                act[b] = a;
                ss += a * a;
            }
            float rr = 1.0f / fmaxf(sqrtf(ss), 1e-12f);
            #pragma unroll
            for (int i2 = 0; i2 < 10; i2++) {
                u32 lo = f2bf(act[2 * i2] * rr);
                u32 hi = f2bf(act[2 * i2 + 1] * rr);
                packed[jj * 10 + i2] = lo | (hi << 16);
            }
        }
        uint4* zp = (uint4*)(z + ((size_t)(bm + row) * FDIM + c * 80));
        #pragma unroll
        for (int u2 = 0; u2 < 10; u2++)
            zp[u2] = make_uint4(packed[4*u2], packed[4*u2+1], packed[4*u2+2], packed[4*u2+3]);
    }
}

// ---------------------------------------------------------------------------
// K6: GEMM2 bf16 MFMA (m97 structure), XCD-swizzled. UNCHANGED this round
// (FETCH 82MB = ideal after T1; next lever is the 256^2 8-phase port).
__global__ __launch_bounds__(256) void k_gemm2(const u16* __restrict__ A,
                                               const u16* __restrict__ B,
                                               float* __restrict__ C) {
    const int K = FDIM, N = EDIM;
    __shared__ u16 As[128 * 32];
    __shared__ u16 Bs[128 * 32];
    int t = threadIdx.x;
    int lane = t & 63, wave = t >> 6;
    int sfl  = (blockIdx.y << 3) | blockIdx.x;        // hw dispatch order (x fastest)
    int tile = ((sfl & 7) << 8) | (sfl >> 3);         // xcd*256 + idx-in-xcd
    int bm = (tile >> 3) * 128;                       // 0..255 M-tiles
    int bn = (tile & 7) * 128;                        // 0..7   N-tiles
    int wm = (wave >> 1) * 64, wn = (wave & 1) * 64;
    int m16 = lane & 15, q = lane >> 4;

    f32x4 zero = {0.f, 0.f, 0.f, 0.f};
    f32x4 acc[4][4];
    #pragma unroll
    for (int i = 0; i < 4; i++)
        #pragma unroll
        for (int j = 0; j < 4; j++) acc[i][j] = zero;

    int sr = t >> 2;
    int sc = (t & 3) * 8;
    const u16* ga = A + (size_t)(bm + sr) * K + sc;
    const u16* gb = B + (size_t)(bn + sr) * K + sc;
    u16* la = &As[sr * 32 + sc];
    u16* lb = &Bs[sr * 32 + sc];

    for (int k0 = 0; k0 < K; k0 += 32) {
        gl_lds16(ga + k0,                 la);
        gl_lds16(ga + k0 + (size_t)64*K,  la + 64 * 32);
        gl_lds16(gb + k0,                 lb);
        gl_lds16(gb + k0 + (size_t)64*K,  lb + 64 * 32);
        __syncthreads();
        bf16x8 af[4], bfr[4];
        #pragma unroll
        for (int i = 0; i < 4; i++)
            af[i] = *(const bf16x8*)&As[(wm + i * 16 + m16) * 32 + q * 8];
        #pragma unroll
        for (int j = 0; j < 4; j++)
            bfr[j] = *(const bf16x8*)&Bs[(wn + j * 16 + m16) * 32 + q * 8];
        #pragma unroll
        for (int i = 0; i < 4; i++)
            #pragma unroll
            for (int j = 0; j < 4; j++)
                acc[i][j] = __builtin_amdgcn_mfma_f32_16x16x32_bf16(
                    af[i], bfr[j], acc[i][j], 0, 0, 0);
        __syncthreads();
    }
    #pragma unroll
    for (int i = 0; i < 4; i++)
        #pragma unroll
        for (int j = 0; j < 4; j++)
            #pragma unroll
            for (int r = 0; r < 4; r++) {
                int row = bm + wm + i * 16 + q * 4 + r;
                int col = bn + wn + j * 16 + m16;
                C[(size_t)row * N + col] = acc[i][j][r];
            }
}

// ---------------------------------------------------------------------------
extern "C" void kernel_launch(void* const* d_in, const int* in_sizes, int n_in,
                              void* d_out, int out_size, void* d_ws, size_t ws_size,
                              hipStream_t stream) {
    const float* x    = (const float*)d_in[0];   // [32768][1024]
    const float* pw   = (const float*)d_in[1];   // [64][1024]
    const float* mean = (const float*)d_in[2];   // [64][20]
    const float* emb  = (const float*)d_in[3];   // [1024][1280]
    float* out = (float*)d_out;                  // [32768][1024] fp32

    char* ws = (char*)d_ws;
    u16*   z    = (u16*)(ws);                    // 83,886,080 B
    u16*   wswh = (u16*)(ws + 83886080);         //    131,072 B (16 swizzled 8KB tiles)
    u16*   wswl = (u16*)(ws + 84017152);         //    131,072 B
    u16*   embW = (u16*)(ws + 84148224);         //  2,621,440 B
    // total: 86,769,664 B

    k_norm_w<<<64, 256, 0, stream>>>(pw, wswh, wswl);
    k_cvt<<<(EDIM * FDIM / 4) / 256, 256, 0, stream>>>(emb, embW);
    k_fused<<<M_ROWS / 64, 256, 0, stream>>>(x, wswh, wswl, mean, z);
    k_gemm2<<<dim3(EDIM / 128, M_ROWS / 128), 256, 0, stream>>>(z, embW, out);
}